// Round 6
// baseline (279.127 us; speedup 1.0000x reference)
//
#include <hip/hip_runtime.h>
#include <hip/hip_bf16.h>

// MultiHeadAttentionBlock on MI355X (gfx950), bf16 MFMA pipeline.
// B=2, L=2048, D=1024, H=16, DK=64.
//
// Memory plan (lifetimes disjoint, 32 MiB ws + d_out-as-scratch):
//   d_out (16 MB):  [q_bf 8MB][k_bf 8MB]   -> overwritten by final out-proj
//   ws    (32 MB):  [v_bf 8MB][qkv 24MB]   ; attnout (8MB) reuses v_bf region
// Pipeline: cast3 (q,k,v -> bf16) ; gemm_k QKV (A via global_load_lds bf16,
// W f32 reg-staged) ; attn ; gemm_k out-proj -> d_out f32.

#define DEVINL __device__ __forceinline__

typedef __attribute__((ext_vector_type(8))) short short8;   // 8 x bf16 bits
typedef __attribute__((ext_vector_type(4))) float floatx4;  // MFMA C/D frag

static constexpr int Bq = 2, Lq = 2048, Dm = 1024;
static constexpr int Mrows = Bq * Lq;   // 4096
static constexpr size_t QKV_LD = 3072;  // packed Q|K|V row stride
static constexpr int NT = Lq / 64;      // 32 key tiles

DEVINL unsigned short f2bf(float x) {
  __hip_bfloat16 h = __float2bfloat16(x);
  unsigned short u;
  __builtin_memcpy(&u, &h, 2);
  return u;
}

DEVINL float bf2f(unsigned short u) {
  unsigned int t = ((unsigned int)u) << 16;
  float f;
  __builtin_memcpy(&f, &t, 4);
  return f;
}

DEVINL short8 cvt8(float4 a, float4 b) {
  union { unsigned short u[8]; short8 v; } o;
  o.u[0] = f2bf(a.x); o.u[1] = f2bf(a.y); o.u[2] = f2bf(a.z); o.u[3] = f2bf(a.w);
  o.u[4] = f2bf(b.x); o.u[5] = f2bf(b.y); o.u[6] = f2bf(b.z); o.u[7] = f2bf(b.w);
  return o.v;
}

DEVINL void gll16(const void* g, const void* l) {
  auto gp = (const __attribute__((address_space(1))) char*)(unsigned long long)(uintptr_t)g;
  auto lp = (__attribute__((address_space(3))) char*)(unsigned int)(uintptr_t)l;
  __builtin_amdgcn_global_load_lds(gp, lp, 16, 0, 0);
}

// ---------------- cast f32 -> bf16, 3 tensors in one launch ----------------
__global__ __launch_bounds__(256) void cast3(const float* __restrict__ q,
                                             const float* __restrict__ k,
                                             const float* __restrict__ v,
                                             unsigned short* __restrict__ dq,
                                             unsigned short* __restrict__ dk,
                                             unsigned short* __restrict__ dv) {
  const int z = blockIdx.y;
  const float* s = (z == 0) ? q : ((z == 1) ? k : v);
  unsigned short* d = (z == 0) ? dq : ((z == 1) ? dk : dv);
  int i = blockIdx.x * 256 + threadIdx.x;
  float4 a = ((const float4*)s)[i * 2];
  float4 b = ((const float4*)s)[i * 2 + 1];
  ((short8*)d)[i] = cvt8(a, b);
}

// ---------------- GEMM: C = A @ W^T + bias ----------------
// A: (M,K) bf16 via global_load_lds; W: (N,K) f32 reg-staged + cvt.
// 128x128 tile, BK=32, 4 waves, LDS double-buffered, one barrier per K-step.
// 1-D grid, XCD-group swizzle (8 consecutive blocks -> 8 XCDs; groups of 8
// share an A-panel; an XCD's successive groups reuse the same W panels).
template <bool OUT_BF16>
__global__ __launch_bounds__(256) void gemm_k(
    const unsigned short* __restrict__ A0, const unsigned short* __restrict__ A1,
    const unsigned short* __restrict__ A2,
    const float* __restrict__ W0, const float* __restrict__ W1, const float* __restrict__ W2,
    const float* __restrict__ b0, const float* __restrict__ b1, const float* __restrict__ b2,
    void* __restrict__ Cout, int M, int N, int K, int ldc) {
  const int bid = blockIdx.x;
  const int xcd = bid & 7, sl = bid >> 3;
  const int g = xcd + ((sl >> 3) << 3), jn = sl & 7;
  const int z = g >> 5;
  const int m0 = (g & 31) * 128, n0 = jn * 128;

  const unsigned short* A = (z == 0) ? A0 : ((z == 1) ? A1 : A2);
  const float* W = (z == 0) ? W0 : ((z == 1) ? W1 : W2);
  const float* bias = (z == 0) ? b0 : ((z == 1) ? b1 : b2);
  const int tid = threadIdx.x, lane = tid & 63, w = tid >> 6;
  const int wr = w >> 1, wc = w & 1;

  __shared__ __align__(16) unsigned short As[2][128 * 32];
  __shared__ __align__(16) unsigned short Bs[2][128 * 32];

  floatx4 acc[4][4] = {};
  float4 wreg[2][2];

  auto loadW = [&](int kt) {
#pragma unroll
    for (int it = 0; it < 2; ++it) {
      int gg = it * 256 + tid, row = gg >> 2, gk = gg & 3;
      const float* p = W + (size_t)(n0 + row) * K + kt + gk * 8;
      wreg[it][0] = ((const float4*)p)[0];
      wreg[it][1] = ((const float4*)p)[1];
    }
  };
  auto writeW = [&](int buf) {
#pragma unroll
    for (int it = 0; it < 2; ++it) {
      int gg = it * 256 + tid, row = gg >> 2, gk = gg & 3;
      *(short8*)((char*)Bs + buf * 8192 + row * 64 + ((gk ^ (row & 3)) << 4)) =
          cvt8(wreg[it][0], wreg[it][1]);
    }
  };
  auto stageA = [&](int kt, int buf) {
#pragma unroll
    for (int it = 0; it < 2; ++it) {
      int gg = it * 256 + tid, row = gg >> 2, gk = gg & 3;
      int koff = (gk ^ (row & 3)) * 8;
      gll16(A + (size_t)(m0 + row) * K + kt + koff,
            (const char*)As + buf * 8192 + (it * 256 + w * 64) * 16);
    }
  };

  const int nt = K / 32;
  // prologue: stage tile 0 -> buf0; issue W loads for tile 1
  loadW(0);
  stageA(0, 0);
  writeW(0);
  if (nt > 1) loadW(32);
  __syncthreads();

  const int krow = lane >> 4;
  for (int t = 0; t < nt; ++t) {
    const int c = t & 1, n = c ^ 1;
    // issue async A-stage for t+1 first (max slack before the barrier drain),
    // then W regs->LDS (loaded one iteration ago), then W loads for t+2
    if (t + 1 < nt) {
      stageA((t + 1) * 32, n);
      writeW(n);
      if (t + 2 < nt) loadW((t + 2) * 32);
    }
    // frag reads for tile t (buf c)
    short8 af[4], bfr[4];
#pragma unroll
    for (int m = 0; m < 4; ++m) {
      int row = wr * 64 + m * 16 + (lane & 15);
      af[m] = *(const short8*)((const char*)As + c * 8192 + row * 64 + ((krow ^ (row & 3)) << 4));
    }
#pragma unroll
    for (int n2 = 0; n2 < 4; ++n2) {
      int row = wc * 64 + n2 * 16 + (lane & 15);
      bfr[n2] = *(const short8*)((const char*)Bs + c * 8192 + row * 64 + ((krow ^ (row & 3)) << 4));
    }
    __builtin_amdgcn_s_setprio(1);
#pragma unroll
    for (int m = 0; m < 4; ++m)
#pragma unroll
      for (int n2 = 0; n2 < 4; ++n2)
        acc[m][n2] = __builtin_amdgcn_mfma_f32_16x16x32_bf16(af[m], bfr[n2], acc[m][n2], 0, 0, 0);
    __builtin_amdgcn_s_setprio(0);
    __syncthreads();
  }

  const int r4 = lane >> 4;
#pragma unroll
  for (int m = 0; m < 4; ++m)
#pragma unroll
    for (int n2 = 0; n2 < 4; ++n2) {
      int col = n0 + wc * 64 + n2 * 16 + (lane & 15);
      float bv = bias[col];
#pragma unroll
      for (int r = 0; r < 4; ++r) {
        int row = m0 + wr * 64 + m * 16 + r4 * 4 + r;
        float v = acc[m][n2][r] + bv;
        if (OUT_BF16)
          ((unsigned short*)Cout)[(size_t)row * ldc + (size_t)z * N + col] = f2bf(v);
        else
          ((float*)Cout)[(size_t)row * ldc + (size_t)z * N + col] = v;
      }
    }
}

// ---------------- flash attention (unchanged from round 5) ----------------
__global__ __launch_bounds__(256) void attn_kernel(const unsigned short* __restrict__ QKV,
                                                   const int* __restrict__ mask,
                                                   unsigned short* __restrict__ Aout) {
  const int bid = blockIdx.x;
  const int xcd = bid & 7, sl = bid >> 3;
  const int bh = xcd + ((sl >> 5) << 3);
  const int q0 = (sl & 31) * 64;
  const int b = bh >> 4, h = bh & 15;
  const int tid = threadIdx.x, lane = tid & 63, w = tid >> 6;

  __shared__ __align__(16) unsigned short Klds[2][64 * 64];
  __shared__ __align__(16) unsigned short Vtlds[2][64 * 64];
  __shared__ __align__(16) unsigned short Plds[4][16 * 64];
  __shared__ int mflag[NT];

  const unsigned short* base = QKV + (size_t)b * Lq * QKV_LD;
  const unsigned short* Kbase = base + 1024;
  const unsigned short* Vbase = base + 2048;

  const int kp = tid & 31;
  const int vd0 = (tid >> 5) * 8;

  auto stageK = [&](int t, int buf) {
#pragma unroll
    for (int it = 0; it < 2; ++it) {
      int g = it * 256 + tid, key = g >> 3, gk = g & 7;
      gll16(Kbase + (size_t)(t * 64 + key) * QKV_LD + h * 64 + (gk ^ (key & 7)) * 8,
            (const char*)Klds + buf * 8192 + (it * 256 + w * 64) * 16);
    }
  };
  short8 vr0, vr1;
  auto loadV = [&](int t) {
    vr0 = *(const short8*)(Vbase + (size_t)(t * 64 + 2 * kp) * QKV_LD + h * 64 + vd0);
    vr1 = *(const short8*)(Vbase + (size_t)(t * 64 + 2 * kp + 1) * QKV_LD + h * 64 + vd0);
  };
  auto writeV = [&](int buf) {
#pragma unroll
    for (int i = 0; i < 8; ++i) {
      int d = vd0 + i;
      unsigned int val = (unsigned int)(unsigned short)vr0[i] |
                         ((unsigned int)(unsigned short)vr1[i] << 16);
      *(unsigned int*)((char*)Vtlds + buf * 8192 + d * 128 + (((kp >> 2) ^ (d & 7)) << 4) +
                       (kp & 3) * 4) = val;
    }
  };

  stageK(0, 0);
  loadV(0);
  writeV(0);
  {
    const int* mp = mask + b * Lq + tid * 8;
    int4 a = ((const int4*)mp)[0], bb = ((const int4*)mp)[1];
    int myall = (a.x && a.y && a.z && a.w && bb.x && bb.y && bb.z && bb.w) ? 1 : 0;
    unsigned long long bal = __ballot(myall);
    if (lane < 8) mflag[w * 8 + lane] = (((bal >> (lane * 8)) & 0xffull) == 0xffull);
  }

  short8 qf[2];
  {
    int row = q0 + w * 16 + (lane & 15);
#pragma unroll
    for (int c = 0; c < 2; ++c) {
      short8 raw = *(const short8*)(base + (size_t)row * QKV_LD + h * 64 + c * 32 + (lane >> 4) * 8);
      union { unsigned short u[8]; short8 v; } o2;
#pragma unroll
      for (int i = 0; i < 8; ++i) o2.u[i] = f2bf(bf2f((unsigned short)raw[i]) * 0.18033688f);
      qf[c] = o2.v;
    }
  }
  union { unsigned short u[8]; short8 v; } one_u;
#pragma unroll
  for (int i = 0; i < 8; ++i) one_u.u[i] = 0x3F80;
  const short8 ones8 = one_u.v;

  __syncthreads();

  floatx4 o[4] = {};
  floatx4 lacc = {};
  float mrow[4];
#pragma unroll
  for (int r = 0; r < 4; ++r) mrow[r] = -1e30f;

  for (int t = 0; t < NT; ++t) {
    const int c = t & 1, n = c ^ 1;
    if (t + 1 < NT) { stageK(t + 1, n); loadV(t + 1); }

    floatx4 s[4] = {};
    __builtin_amdgcn_s_setprio(1);
#pragma unroll
    for (int f = 0; f < 4; ++f) {
      int key = f * 16 + (lane & 15);
#pragma unroll
      for (int c2 = 0; c2 < 2; ++c2) {
        short8 kf = *(const short8*)((const char*)Klds + c * 8192 + key * 128 +
                                     (((c2 * 4 + (lane >> 4)) ^ (key & 7)) << 4));
        s[f] = __builtin_amdgcn_mfma_f32_16x16x32_bf16(qf[c2], kf, s[f], 0, 0, 0);
      }
    }
    __builtin_amdgcn_s_setprio(0);

    float tmax[4];
#pragma unroll
    for (int r = 0; r < 4; ++r)
      tmax[r] = fmaxf(fmaxf(s[0][r], s[1][r]), fmaxf(s[2][r], s[3][r]));
    const int allm = mflag[t];
    bool ok = (tmax[0] <= mrow[0] + 11.5f) && (tmax[1] <= mrow[1] + 11.5f) &&
              (tmax[2] <= mrow[2] + 11.5f) && (tmax[3] <= mrow[3] + 11.5f);
    if (__ballot(ok && allm) == ~0ull) {
#pragma unroll
      for (int f = 0; f < 4; ++f)
#pragma unroll
        for (int r = 0; r < 4; ++r) s[f][r] = __builtin_amdgcn_exp2f(s[f][r] - mrow[r]);
    } else {
#pragma unroll
      for (int dx = 1; dx <= 8; dx <<= 1)
#pragma unroll
        for (int r = 0; r < 4; ++r) tmax[r] = fmaxf(tmax[r], __shfl_xor(tmax[r], dx, 64));
      float mnew[4], alpha[4];
#pragma unroll
      for (int r = 0; r < 4; ++r) {
        mnew[r] = fmaxf(mrow[r], tmax[r]);
        alpha[r] = __builtin_amdgcn_exp2f(mrow[r] - mnew[r]);
        mrow[r] = mnew[r];
      }
#pragma unroll
      for (int df = 0; df < 4; ++df)
#pragma unroll
        for (int r = 0; r < 4; ++r) o[df][r] *= alpha[r];
#pragma unroll
      for (int r = 0; r < 4; ++r) lacc[r] *= alpha[r];
      if (allm) {
#pragma unroll
        for (int f = 0; f < 4; ++f)
#pragma unroll
          for (int r = 0; r < 4; ++r) s[f][r] = __builtin_amdgcn_exp2f(s[f][r] - mnew[r]);
      } else {
#pragma unroll
        for (int f = 0; f < 4; ++f) {
          int mv = mask[b * Lq + t * 64 + f * 16 + (lane & 15)];
#pragma unroll
          for (int r = 0; r < 4; ++r)
            s[f][r] = mv ? __builtin_amdgcn_exp2f(s[f][r] - mnew[r]) : 0.f;
        }
      }
    }

#pragma unroll
    for (int f = 0; f < 4; ++f)
#pragma unroll
      for (int r = 0; r < 4; ++r) {
        int row = (lane >> 4) * 4 + r, col = f * 16 + (lane & 15);
        *(unsigned short*)((char*)&Plds[w][0] + row * 128 + (((col >> 3) ^ (row & 7)) << 4) +
                           (col & 7) * 2) = f2bf(s[f][r]);
      }

    short8 pf[2];
#pragma unroll
    for (int kc = 0; kc < 2; ++kc)
      pf[kc] = *(const short8*)((const char*)&Plds[w][0] + (lane & 15) * 128 +
                                (((kc * 4 + (lane >> 4)) ^ (lane & 7)) << 4));
    __builtin_amdgcn_s_setprio(1);
    lacc = __builtin_amdgcn_mfma_f32_16x16x32_bf16(pf[0], ones8, lacc, 0, 0, 0);
    lacc = __builtin_amdgcn_mfma_f32_16x16x32_bf16(pf[1], ones8, lacc, 0, 0, 0);
#pragma unroll
    for (int df = 0; df < 4; ++df) {
      int d = df * 16 + (lane & 15);
#pragma unroll
      for (int kc = 0; kc < 2; ++kc) {
        short8 vf = *(const short8*)((const char*)Vtlds + c * 8192 + d * 128 +
                                     (((kc * 4 + (lane >> 4)) ^ (d & 7)) << 4));
        o[df] = __builtin_amdgcn_mfma_f32_16x16x32_bf16(pf[kc], vf, o[df], 0, 0, 0);
      }
    }
    __builtin_amdgcn_s_setprio(0);

    if (t + 1 < NT) writeV(n);
    __syncthreads();
  }

  float rl[4];
#pragma unroll
  for (int r = 0; r < 4; ++r) rl[r] = 1.0f / lacc[r];
#pragma unroll
  for (int df = 0; df < 4; ++df)
#pragma unroll
    for (int r = 0; r < 4; ++r) {
      int row = q0 + w * 16 + (lane >> 4) * 4 + r;
      int col = h * 64 + df * 16 + (lane & 15);
      Aout[(size_t)(b * Lq + row) * Dm + col] = f2bf(o[df][r] * rl[r]);
    }
}

// ---------------- launcher ----------------
extern "C" void kernel_launch(void* const* d_in, const int* in_sizes, int n_in,
                              void* d_out, int out_size, void* d_ws, size_t ws_size,
                              hipStream_t stream) {
  const float* q = (const float*)d_in[0];
  const float* k = (const float*)d_in[1];
  const float* v = (const float*)d_in[2];
  const int* maskp = (const int*)d_in[3];
  const float* wq = (const float*)d_in[4];
  const float* bq = (const float*)d_in[5];
  const float* wk = (const float*)d_in[6];
  const float* bk = (const float*)d_in[7];
  const float* wv = (const float*)d_in[8];
  const float* bv = (const float*)d_in[9];
  const float* wo = (const float*)d_in[10];
  const float* bo = (const float*)d_in[11];

  const size_t nIn = (size_t)Mrows * Dm;  // 4 Mi elems

  // d_out as early scratch (fully overwritten by out-proj at the end)
  unsigned short* q_bf = (unsigned short*)d_out;  // 8 MB
  unsigned short* k_bf = q_bf + nIn;              // 8 MB
  // ws
  unsigned short* v_bf = (unsigned short*)d_ws;           // 8 MB (dead after QKV gemm)
  unsigned short* qkv = v_bf + nIn;                       // 24 MB
  unsigned short* attnout = (unsigned short*)d_ws;        // reuses v_bf region

  // casts: q,k -> d_out scratch; v -> ws
  cast3<<<dim3(nIn / 8 / 256, 3), 256, 0, stream>>>(q, k, v, q_bf, k_bf, v_bf);

  // QKV projections (768 blocks = 3z x 32m x 8n, XCD-swizzled)
  gemm_k<true><<<dim3(768), 256, 0, stream>>>(
      q_bf, k_bf, v_bf, wq, wk, wv, bq, bk, bv, qkv, Mrows, Dm, Dm, (int)QKV_LD);

  // attention (1024 blocks, XCD-swizzled); writes attnout over v_bf
  attn_kernel<<<dim3(1024), 256, 0, stream>>>(qkv, maskp, attnout);

  // output projection -> f32 d_out (overwrites q_bf/k_bf scratch)
  gemm_k<false><<<dim3(256), 256, 0, stream>>>(
      attnout, attnout, attnout, wo, wo, wo, bo, bo, bo, d_out, Mrows, Dm, Dm, Dm);
}

// Round 9
// 255.669 us; speedup vs baseline: 1.0918x; 1.0918x over previous
//
#include <hip/hip_runtime.h>
#include <hip/hip_bf16.h>

// MultiHeadAttentionBlock on MI355X (gfx950), bf16 MFMA pipeline.
// B=2, L=2048, D=1024, H=16, DK=64.
//
// Memory plan (all lifetimes disjoint):
//   d_out (16 MB): [wq_bf|wk_bf|wv_bf 6 MB][10 MB free] -> final f32 output
//   ws    (32 MB): [attnout 8 MB][qkv 24 MB]; wo_bf (2 MB) reuses dead qkv
//     head after attn.
// Pipeline: castw (wq,wk,wv->bf16) ; gemm QKV (A=f32 reg-staged, W=bf16 via
// global_load_lds, z-major XCD map) ; attn (8-wave, QBLK=128) ; castw1 (wo) ;
// gemm out-proj (A=bf16 gll16, W=bf16 gll16) -> d_out f32.

#define DEVINL __device__ __forceinline__

typedef __attribute__((ext_vector_type(8))) short short8;   // 8 x bf16 bits
typedef __attribute__((ext_vector_type(4))) float floatx4;  // MFMA C/D frag

static constexpr int Bq = 2, Lq = 2048, Dm = 1024;
static constexpr int Mrows = Bq * Lq;   // 4096
static constexpr size_t QKV_LD = 3072;  // packed Q|K|V row stride
static constexpr int NT = Lq / 64;      // 32 key tiles
static constexpr size_t NW = (size_t)Dm * Dm;  // 1 Mi elems per weight matrix

DEVINL unsigned short f2bf(float x) {
  __hip_bfloat16 h = __float2bfloat16(x);
  unsigned short u;
  __builtin_memcpy(&u, &h, 2);
  return u;
}

DEVINL float bf2f(unsigned short u) {
  unsigned int t = ((unsigned int)u) << 16;
  float f;
  __builtin_memcpy(&f, &t, 4);
  return f;
}

DEVINL short8 cvt8(float4 a, float4 b) {
  union { unsigned short u[8]; short8 v; } o;
  o.u[0] = f2bf(a.x); o.u[1] = f2bf(a.y); o.u[2] = f2bf(a.z); o.u[3] = f2bf(a.w);
  o.u[4] = f2bf(b.x); o.u[5] = f2bf(b.y); o.u[6] = f2bf(b.z); o.u[7] = f2bf(b.w);
  return o.v;
}

DEVINL void gll16(const void* g, const void* l) {
  auto gp = (const __attribute__((address_space(1))) char*)(unsigned long long)(uintptr_t)g;
  auto lp = (__attribute__((address_space(3))) char*)(unsigned int)(uintptr_t)l;
  __builtin_amdgcn_global_load_lds(gp, lp, 16, 0, 0);
}

// ---------------- weight casts ----------------
__global__ __launch_bounds__(256) void castw(const float* __restrict__ w0,
                                             const float* __restrict__ w1,
                                             const float* __restrict__ w2,
                                             unsigned short* __restrict__ dst) {
  const int z = blockIdx.y;
  const float* s = (z == 0) ? w0 : ((z == 1) ? w1 : w2);
  int i = blockIdx.x * 256 + threadIdx.x;
  float4 a = ((const float4*)s)[i * 2];
  float4 b = ((const float4*)s)[i * 2 + 1];
  ((short8*)(dst + (size_t)z * NW))[i] = cvt8(a, b);
}

__global__ __launch_bounds__(256) void castw1(const float* __restrict__ s,
                                              unsigned short* __restrict__ dst) {
  int i = blockIdx.x * 256 + threadIdx.x;
  float4 a = ((const float4*)s)[i * 2];
  float4 b = ((const float4*)s)[i * 2 + 1];
  ((short8*)dst)[i] = cvt8(a, b);
}

// ---------------- GEMM: C = A @ W^T + bias ----------------
// 128x128 tile, BK=32, 4 waves, LDS dbuf, one barrier per K-step.
// W: bf16 via global_load_lds (z-strided from Wb). A: bf16 gll16 (A_BF16) or
// f32 reg-staged + cvt. Grid 1-D, z-major XCD map: xcd=bid&7, G=xcd*GPX+q so
// each XCD's resident W working set is 1-2 z's (2-4 MB bf16, L2-resident).
template <bool A_BF16, bool OUT_BF16>
__global__ __launch_bounds__(256) void gemm_k(
    const void* __restrict__ A0, const void* __restrict__ A1, const void* __restrict__ A2,
    const unsigned short* __restrict__ Wb,
    const float* __restrict__ b0, const float* __restrict__ b1, const float* __restrict__ b2,
    void* __restrict__ Cout, int M, int N, int K, int ldc, int GPX) {
  const int bid = blockIdx.x;
  const int xcd = bid & 7, rest = bid >> 3;
  const int qg = rest >> 3, jn = rest & 7;
  const int G = xcd * GPX + qg;
  const int z = G >> 5;
  const int m0 = (G & 31) * 128, n0 = jn * 128;

  const void* Aany = (z == 0) ? A0 : ((z == 1) ? A1 : A2);
  const unsigned short* W = Wb + (size_t)z * N * K;
  const float* bias = (z == 0) ? b0 : ((z == 1) ? b1 : b2);
  const int tid = threadIdx.x, lane = tid & 63, w = tid >> 6;
  const int wr = w >> 1, wc = w & 1;

  __shared__ __align__(16) unsigned short As[2][128 * 32];
  __shared__ __align__(16) unsigned short Bs[2][128 * 32];

  floatx4 acc[4][4] = {};
  float4 areg[2][2];

  auto stageW = [&](int kt, int buf) {
#pragma unroll
    for (int it = 0; it < 2; ++it) {
      int gg = it * 256 + tid, row = gg >> 2, gk = gg & 3;
      int koff = (gk ^ (row & 3)) * 8;
      gll16(W + (size_t)(n0 + row) * K + kt + koff,
            (const char*)Bs + buf * 8192 + (it * 256 + w * 64) * 16);
    }
  };
  auto stageA = [&](int kt, int buf) {
#pragma unroll
    for (int it = 0; it < 2; ++it) {
      int gg = it * 256 + tid, row = gg >> 2, gk = gg & 3;
      int koff = (gk ^ (row & 3)) * 8;
      gll16((const unsigned short*)Aany + (size_t)(m0 + row) * K + kt + koff,
            (const char*)As + buf * 8192 + (it * 256 + w * 64) * 16);
    }
  };
  auto loadA = [&](int kt) {
#pragma unroll
    for (int it = 0; it < 2; ++it) {
      int gg = it * 256 + tid, row = gg >> 2, gk = gg & 3;
      const float* p = (const float*)Aany + (size_t)(m0 + row) * K + kt + gk * 8;
      areg[it][0] = ((const float4*)p)[0];
      areg[it][1] = ((const float4*)p)[1];
    }
  };
  auto writeA = [&](int buf) {
#pragma unroll
    for (int it = 0; it < 2; ++it) {
      int gg = it * 256 + tid, row = gg >> 2, gk = gg & 3;
      *(short8*)((char*)As + buf * 8192 + row * 64 + ((gk ^ (row & 3)) << 4)) =
          cvt8(areg[it][0], areg[it][1]);
    }
  };

  const int nt = K / 32;
  // prologue
  if (!A_BF16) loadA(0);
  stageW(0, 0);
  if (A_BF16) stageA(0, 0); else writeA(0);
  if (!A_BF16 && nt > 1) loadA(32);
  __syncthreads();

  const int krow = lane >> 4;
  for (int t = 0; t < nt; ++t) {
    const int c = t & 1, n = c ^ 1;
    // stage tile t+1 (async + reg->LDS) before compute: full MFMA phase of slack
    if (t + 1 < nt) {
      stageW((t + 1) * 32, n);
      if (A_BF16) {
        stageA((t + 1) * 32, n);
      } else {
        writeA(n);
        if (t + 2 < nt) loadA((t + 2) * 32);
      }
    }
    short8 af[4], bfr[4];
#pragma unroll
    for (int m = 0; m < 4; ++m) {
      int row = wr * 64 + m * 16 + (lane & 15);
      af[m] = *(const short8*)((const char*)As + c * 8192 + row * 64 + ((krow ^ (row & 3)) << 4));
    }
#pragma unroll
    for (int n2 = 0; n2 < 4; ++n2) {
      int row = wc * 64 + n2 * 16 + (lane & 15);
      bfr[n2] = *(const short8*)((const char*)Bs + c * 8192 + row * 64 + ((krow ^ (row & 3)) << 4));
    }
    __builtin_amdgcn_s_setprio(1);
#pragma unroll
    for (int m = 0; m < 4; ++m)
#pragma unroll
      for (int n2 = 0; n2 < 4; ++n2)
        acc[m][n2] = __builtin_amdgcn_mfma_f32_16x16x32_bf16(af[m], bfr[n2], acc[m][n2], 0, 0, 0);
    __builtin_amdgcn_s_setprio(0);
    __syncthreads();
  }

  const int r4 = lane >> 4;
#pragma unroll
  for (int m = 0; m < 4; ++m)
#pragma unroll
    for (int n2 = 0; n2 < 4; ++n2) {
      int col = n0 + wc * 64 + n2 * 16 + (lane & 15);
      float bv = bias[col];
#pragma unroll
      for (int r = 0; r < 4; ++r) {
        int row = m0 + wr * 64 + m * 16 + r4 * 4 + r;
        float v = acc[m][n2][r] + bv;
        if (OUT_BF16)
          ((unsigned short*)Cout)[(size_t)row * ldc + (size_t)z * N + col] = f2bf(v);
        else
          ((float*)Cout)[(size_t)row * ldc + (size_t)z * N + col] = v;
      }
    }
}

// ---------------- flash attention ----------------
// 512 threads = 8 waves, QBLK=128 (wave w owns q rows [q0+16w, q0+16w+16)).
// K/V staging amortized over 8 waves; K/Vt dbuf; one barrier per 64-key tile.
// Grid 512 blocks, XCD map: 4 bh x 16 q-blocks per XCD (K/V L2-resident).
__global__ __launch_bounds__(512) void attn_kernel(const unsigned short* __restrict__ QKV,
                                                   const int* __restrict__ mask,
                                                   unsigned short* __restrict__ Aout) {
  const int bid = blockIdx.x;
  const int xcd = bid & 7, sl = bid >> 3;
  const int bh = xcd + ((sl >> 4) << 3);
  const int q0 = (sl & 15) * 128;
  const int b = bh >> 4, h = bh & 15;
  const int tid = threadIdx.x, lane = tid & 63, w = tid >> 6;

  __shared__ __align__(16) unsigned short Klds[2][64 * 64];   // 16 KB
  __shared__ __align__(16) unsigned short Vtlds[2][64 * 64];  // 16 KB
  __shared__ __align__(16) unsigned short Plds[8][16 * 64];   // 16 KB
  __shared__ int mflag[NT];

  const unsigned short* base = QKV + (size_t)b * Lq * QKV_LD;
  const unsigned short* Kbase = base + 1024;
  const unsigned short* Vbase = base + 2048;

  const int kp = tid & 31;                // key-pair (V), tid<256 only
  const int vd0 = ((tid >> 5) & 7) * 8;   // d-chunk base (V), tid<256 only

  auto stageK = [&](int t, int buf) {
    int key = tid >> 3, gk = tid & 7;
    gll16(Kbase + (size_t)(t * 64 + key) * QKV_LD + h * 64 + (gk ^ (key & 7)) * 8,
          (const char*)Klds + buf * 8192 + w * 1024);
  };
  short8 vr0, vr1;
  auto loadV = [&](int t) {
    vr0 = *(const short8*)(Vbase + (size_t)(t * 64 + 2 * kp) * QKV_LD + h * 64 + vd0);
    vr1 = *(const short8*)(Vbase + (size_t)(t * 64 + 2 * kp + 1) * QKV_LD + h * 64 + vd0);
  };
  auto writeV = [&](int buf) {
#pragma unroll
    for (int i = 0; i < 8; ++i) {
      int d = vd0 + i;
      unsigned int val = (unsigned int)(unsigned short)vr0[i] |
                         ((unsigned int)(unsigned short)vr1[i] << 16);
      *(unsigned int*)((char*)Vtlds + buf * 8192 + d * 128 + (((kp >> 2) ^ (d & 7)) << 4) +
                       (kp & 3) * 4) = val;
    }
  };

  // prologue: stage tile 0; per-tile mask all-ones flags (waves 0-3)
  stageK(0, 0);
  if (tid < 256) {
    loadV(0);
    writeV(0);
    const int* mp = mask + b * Lq + tid * 8;
    int4 a = ((const int4*)mp)[0], bb = ((const int4*)mp)[1];
    int myall = (a.x && a.y && a.z && a.w && bb.x && bb.y && bb.z && bb.w) ? 1 : 0;
    unsigned long long bal = __ballot(myall);
    if (lane < 8) mflag[w * 8 + lane] = (((bal >> (lane * 8)) & 0xffull) == 0xffull);
  }

  // Q fragments, pre-scaled by (1/sqrt(dk)) * log2(e)
  short8 qf[2];
  {
    int row = q0 + w * 16 + (lane & 15);
#pragma unroll
    for (int c = 0; c < 2; ++c) {
      short8 raw = *(const short8*)(base + (size_t)row * QKV_LD + h * 64 + c * 32 + (lane >> 4) * 8);
      union { unsigned short u[8]; short8 v; } o2;
#pragma unroll
      for (int i = 0; i < 8; ++i) o2.u[i] = f2bf(bf2f((unsigned short)raw[i]) * 0.18033688f);
      qf[c] = o2.v;
    }
  }
  union { unsigned short u[8]; short8 v; } one_u;
#pragma unroll
  for (int i = 0; i < 8; ++i) one_u.u[i] = 0x3F80;
  const short8 ones8 = one_u.v;

  __syncthreads();

  floatx4 o[4] = {};
  floatx4 lacc = {};
  float mrow[4];
#pragma unroll
  for (int r = 0; r < 4; ++r) mrow[r] = -1e30f;

  for (int t = 0; t < NT; ++t) {
    const int c = t & 1, n = c ^ 1;
    if (t + 1 < NT) {
      stageK(t + 1, n);
      if (tid < 256) loadV(t + 1);
    }

    // S = Q K^T (16 q x 64 keys per wave), exp2-domain
    floatx4 s[4] = {};
    __builtin_amdgcn_s_setprio(1);
#pragma unroll
    for (int f = 0; f < 4; ++f) {
      int key = f * 16 + (lane & 15);
#pragma unroll
      for (int c2 = 0; c2 < 2; ++c2) {
        short8 kf = *(const short8*)((const char*)Klds + c * 8192 + key * 128 +
                                     (((c2 * 4 + (lane >> 4)) ^ (key & 7)) << 4));
        s[f] = __builtin_amdgcn_mfma_f32_16x16x32_bf16(qf[c2], kf, s[f], 0, 0, 0);
      }
    }
    __builtin_amdgcn_s_setprio(0);

    float tmax[4];
#pragma unroll
    for (int r = 0; r < 4; ++r)
      tmax[r] = fmaxf(fmaxf(s[0][r], s[1][r]), fmaxf(s[2][r], s[3][r]));
    const int allm = mflag[t];
    bool ok = (tmax[0] <= mrow[0] + 11.5f) && (tmax[1] <= mrow[1] + 11.5f) &&
              (tmax[2] <= mrow[2] + 11.5f) && (tmax[3] <= mrow[3] + 11.5f);
    if (__ballot(ok && allm) == ~0ull) {
#pragma unroll
      for (int f = 0; f < 4; ++f)
#pragma unroll
        for (int r = 0; r < 4; ++r) s[f][r] = __builtin_amdgcn_exp2f(s[f][r] - mrow[r]);
    } else {
#pragma unroll
      for (int dx = 1; dx <= 8; dx <<= 1)
#pragma unroll
        for (int r = 0; r < 4; ++r) tmax[r] = fmaxf(tmax[r], __shfl_xor(tmax[r], dx, 64));
      float mnew[4], alpha[4];
#pragma unroll
      for (int r = 0; r < 4; ++r) {
        mnew[r] = fmaxf(mrow[r], tmax[r]);
        alpha[r] = __builtin_amdgcn_exp2f(mrow[r] - mnew[r]);
        mrow[r] = mnew[r];
      }
#pragma unroll
      for (int df = 0; df < 4; ++df)
#pragma unroll
        for (int r = 0; r < 4; ++r) o[df][r] *= alpha[r];
#pragma unroll
      for (int r = 0; r < 4; ++r) lacc[r] *= alpha[r];
      if (allm) {
#pragma unroll
        for (int f = 0; f < 4; ++f)
#pragma unroll
          for (int r = 0; r < 4; ++r) s[f][r] = __builtin_amdgcn_exp2f(s[f][r] - mnew[r]);
      } else {
#pragma unroll
        for (int f = 0; f < 4; ++f) {
          int mv = mask[b * Lq + t * 64 + f * 16 + (lane & 15)];
#pragma unroll
          for (int r = 0; r < 4; ++r)
            s[f][r] = mv ? __builtin_amdgcn_exp2f(s[f][r] - mnew[r]) : 0.f;
        }
      }
    }

    // P -> LDS (bf16), XOR-swizzled, wave-private
#pragma unroll
    for (int f = 0; f < 4; ++f)
#pragma unroll
      for (int r = 0; r < 4; ++r) {
        int row = (lane >> 4) * 4 + r, col = f * 16 + (lane & 15);
        *(unsigned short*)((char*)&Plds[w][0] + row * 128 + (((col >> 3) ^ (row & 7)) << 4) +
                           (col & 7) * 2) = f2bf(s[f][r]);
      }

    // O += P @ V ; l += P @ ones
    short8 pf[2];
#pragma unroll
    for (int kc = 0; kc < 2; ++kc)
      pf[kc] = *(const short8*)((const char*)&Plds[w][0] + (lane & 15) * 128 +
                                (((kc * 4 + (lane >> 4)) ^ (lane & 7)) << 4));
    __builtin_amdgcn_s_setprio(1);
    lacc = __builtin_amdgcn_mfma_f32_16x16x32_bf16(pf[0], ones8, lacc, 0, 0, 0);
    lacc = __builtin_amdgcn_mfma_f32_16x16x32_bf16(pf[1], ones8, lacc, 0, 0, 0);
#pragma unroll
    for (int df = 0; df < 4; ++df) {
      int d = df * 16 + (lane & 15);
#pragma unroll
      for (int kc = 0; kc < 2; ++kc) {
        short8 vf = *(const short8*)((const char*)Vtlds + c * 8192 + d * 128 +
                                     (((kc * 4 + (lane >> 4)) ^ (d & 7)) << 4));
        o[df] = __builtin_amdgcn_mfma_f32_16x16x32_bf16(pf[kc], vf, o[df], 0, 0, 0);
      }
    }
    __builtin_amdgcn_s_setprio(0);

    if (t + 1 < NT && tid < 256) writeV(n);
    __syncthreads();
  }

  float rl[4];
#pragma unroll
  for (int r = 0; r < 4; ++r) rl[r] = 1.0f / lacc[r];
#pragma unroll
  for (int df = 0; df < 4; ++df)
#pragma unroll
    for (int r = 0; r < 4; ++r) {
      int row = q0 + w * 16 + (lane >> 4) * 4 + r;
      int col = h * 64 + df * 16 + (lane & 15);
      Aout[(size_t)(b * Lq + row) * Dm + col] = f2bf(o[df][r] * rl[r]);
    }
}

// ---------------- launcher ----------------
extern "C" void kernel_launch(void* const* d_in, const int* in_sizes, int n_in,
                              void* d_out, int out_size, void* d_ws, size_t ws_size,
                              hipStream_t stream) {
  const float* q = (const float*)d_in[0];
  const float* k = (const float*)d_in[1];
  const float* v = (const float*)d_in[2];
  const int* maskp = (const int*)d_in[3];
  const float* wq = (const float*)d_in[4];
  const float* bq = (const float*)d_in[5];
  const float* wk = (const float*)d_in[6];
  const float* bk = (const float*)d_in[7];
  const float* wv = (const float*)d_in[8];
  const float* bv = (const float*)d_in[9];
  const float* wo = (const float*)d_in[10];
  const float* bo = (const float*)d_in[11];

  // d_out scratch: wq|wk|wv bf16 (6 MB), overwritten by final out-proj
  unsigned short* wqkv_bf = (unsigned short*)d_out;
  // ws: [attnout 8 MB][qkv 24 MB]; wo_bf overlays dead qkv head after attn
  unsigned short* attnout = (unsigned short*)d_ws;
  unsigned short* qkv = attnout + (size_t)Mrows * Dm;
  unsigned short* wo_bf = qkv;  // first 2 MB of qkv region, cast after attn

  // cast wq,wk,wv -> bf16
  castw<<<dim3(NW / 8 / 256, 3), 256, 0, stream>>>(wq, wk, wv, wqkv_bf);

  // QKV projections: 768 blocks (8 xcd x 12 groups x 8 n), z-major XCD map
  gemm_k<false, true><<<dim3(768), 256, 0, stream>>>(
      q, k, v, wqkv_bf, bq, bk, bv, qkv, Mrows, Dm, Dm, (int)QKV_LD, 12);

  // attention: 512 blocks (8 xcd x 4 bh x 16 q-blocks), 8 waves each
  attn_kernel<<<dim3(512), 512, 0, stream>>>(qkv, maskp, attnout);

  // cast wo into dead qkv head
  castw1<<<dim3(NW / 8 / 256), 256, 0, stream>>>(wo, wo_bf);

  // output projection -> f32 d_out (overwrites wqkv_bf scratch)
  gemm_k<true, false><<<dim3(256), 256, 0, stream>>>(
      attnout, attnout, attnout, wo_bf, bo, bo, bo, d_out, Mrows, Dm, Dm, Dm, 4);
}